// Round 3
// baseline (910.189 us; speedup 1.0000x reference)
//
#include <hip/hip_runtime.h>
#include <hip/hip_bf16.h>

typedef unsigned short u16;
typedef __attribute__((ext_vector_type(4))) float f32x4;
typedef __attribute__((ext_vector_type(8))) short bf16x8;
typedef __attribute__((ext_vector_type(4))) unsigned short u16x4;

#define HDIM 2048
#define BM 128
#define BN 128
#define BK 32

__device__ __forceinline__ u16 f2bf(float f) {
  union { float f; unsigned u; } v; v.f = f;
  unsigned r = v.u + 0x7FFFu + ((v.u >> 16) & 1u);
  return (u16)(r >> 16);
}
__device__ __forceinline__ float bf2f(u16 h) {
  union { unsigned u; float f; } v; v.u = ((unsigned)h) << 16;
  return v.f;
}

__device__ __forceinline__ void gload_lds16(const u16* g, void* l) {
  __builtin_amdgcn_global_load_lds(
      (const __attribute__((address_space(1))) unsigned*)g,
      (__attribute__((address_space(3))) unsigned*)l, 16, 0, 0);
}

// ---- cast two f32 [8192][2048] tensors to bf16 ----
__global__ __launch_bounds__(256) void cast_bf(const float* __restrict__ x,
                                               const float* __restrict__ ht,
                                               u16* __restrict__ xb,
                                               u16* __restrict__ hb) {
  const int N4 = 8192 * HDIM / 4;                 // float4 count per tensor
  int idx = blockIdx.x * 256 + threadIdx.x;
  const float* s;
  u16* d;
  int i;
  if (idx < N4) { s = x; d = xb; i = idx; }
  else          { s = ht; d = hb; i = idx - N4; }
  f32x4 v = *(const f32x4*)(s + (size_t)i * 4);
  u16x4 o;
  o.x = f2bf(v.x); o.y = f2bf(v.y); o.z = f2bf(v.z); o.w = f2bf(v.w);
  *(u16x4*)(d + (size_t)i * 4) = o;
}

// ---- transpose + cast: dst[n][k] = bf16(src[k][n]); src is [2048][2048] f32 ----
__global__ __launch_bounds__(256) void transpose_cast(const float* __restrict__ src,
                                                      u16* __restrict__ dst, int dst_ld) {
  __shared__ float tile[32][33];
  int tx = threadIdx.x & 31, ty = threadIdx.x >> 5;
  int n0 = blockIdx.x * 32, k0 = blockIdx.y * 32;
#pragma unroll
  for (int i = 0; i < 32; i += 8)
    tile[ty + i][tx] = src[(size_t)(k0 + ty + i) * HDIM + n0 + tx];
  __syncthreads();
#pragma unroll
  for (int i = 0; i < 32; i += 8)
    dst[(size_t)(n0 + ty + i) * dst_ld + k0 + tx] = f2bf(tile[tx][ty + i]);
}

// ---- GEMM C = [A0|A1](bf16) x Bt(bf16, [N][ldb])^T, fused epilogues ----
// A is split along K: k < K0 reads A0, else A1 (both lda = K0 = 2048).
// EPI 1: gate epilogue (z -> f32 zout, a = sigmoid(.)*ht -> bf16 o_a).
// EPI 2: final GRU combine (reads zout, writes f32 o_final; may alias zout).
template <int EPI>
__global__ __launch_bounds__(256) void gemm2(
    const u16* __restrict__ A0, const u16* __restrict__ A1,
    const u16* __restrict__ Bt, int ldb, int K,
    const float* __restrict__ bias0,   // bz (EPI1) / bh (EPI2)
    const float* __restrict__ bias1,   // br (EPI1)
    const float* __restrict__ htp,     // ht f32
    float* __restrict__ zout,          // EPI1 write / EPI2 read (aliases o_final)
    u16* __restrict__ o_a,             // EPI1 write
    float* __restrict__ o_final)       // EPI2 write
{
  __shared__ __attribute__((aligned(16))) char lds[2 * 16384];
  const int t = threadIdx.x;
  const int lane = t & 63;
  const int w = t >> 6;
  const int wr = w >> 1, wc = w & 1;
  const int m0 = blockIdx.y * BM;
  const int n0 = blockIdx.x * BN;
  const int K0 = K / 2;

  f32x4 acc[4][4];
#pragma unroll
  for (int i = 0; i < 4; ++i)
#pragma unroll
    for (int j = 0; j < 4; ++j)
      acc[i][j] = (f32x4){0.f, 0.f, 0.f, 0.f};

  const int sr = t >> 2;   // staging row 0..63
  const int sc = t & 3;    // staging 16B chunk 0..3
  const int cs1 = sc ^ ((sr >> 1) & 3);
  const int cs2 = sc ^ (((sr + 64) >> 1) & 3);

  auto stage = [&](int buf, int k0) {
    const u16* Ap = (k0 < K0) ? A0 : A1;
    int kk = (k0 < K0) ? k0 : (k0 - K0);
    char* base = lds + buf * 16384;
    gload_lds16(Ap + (size_t)(m0 + sr) * K0 + kk + cs1 * 8, base + t * 16);
    gload_lds16(Ap + (size_t)(m0 + sr + 64) * K0 + kk + cs2 * 8, base + 4096 + t * 16);
    char* bb = base + 8192;
    gload_lds16(Bt + (size_t)(n0 + sr) * ldb + k0 + cs1 * 8, bb + t * 16);
    gload_lds16(Bt + (size_t)(n0 + sr + 64) * ldb + k0 + cs2 * 8, bb + 4096 + t * 16);
  };

  const int NT = K / BK;
  stage(0, 0);
  __syncthreads();
  int cur = 0;
  const int lrow = lane & 15;
  const int khi = lane >> 4;

  for (int tt = 0; tt < NT; ++tt) {
    if (tt + 1 < NT) stage(cur ^ 1, (tt + 1) * BK);
    const char* ab = lds + cur * 16384;
    const char* bb = ab + 8192;
    bf16x8 af[4], bfv[4];
#pragma unroll
    for (int mi = 0; mi < 4; ++mi) {
      int r = wr * 64 + mi * 16 + lrow;
      int off = r * 64 + ((khi ^ ((r >> 1) & 3)) * 16);
      af[mi] = *(const bf16x8*)(ab + off);
    }
#pragma unroll
    for (int ni = 0; ni < 4; ++ni) {
      int r = wc * 64 + ni * 16 + lrow;
      int off = r * 64 + ((khi ^ ((r >> 1) & 3)) * 16);
      bfv[ni] = *(const bf16x8*)(bb + off);
    }
#pragma unroll
    for (int mi = 0; mi < 4; ++mi)
#pragma unroll
      for (int ni = 0; ni < 4; ++ni)
        acc[mi][ni] = __builtin_amdgcn_mfma_f32_16x16x32_bf16(af[mi], bfv[ni], acc[mi][ni], 0, 0, 0);
    __syncthreads();
    cur ^= 1;
  }

  // epilogue: C/D layout col = lane&15, row = (lane>>4)*4 + reg  [m89/m91]
  const int rbase = (lane >> 4) * 4;
  const int cbase = lane & 15;
#pragma unroll
  for (int mi = 0; mi < 4; ++mi) {
#pragma unroll
    for (int ni = 0; ni < 4; ++ni) {
#pragma unroll
      for (int j = 0; j < 4; ++j) {
        int row = m0 + wr * 64 + mi * 16 + rbase + j;
        int col = n0 + wc * 64 + ni * 16 + cbase;
        float v = acc[mi][ni][j];
        if constexpr (EPI == 1) {
          if (col < HDIM) {
            float zv = 1.f / (1.f + __expf(-(v + bias0[col])));
            zout[(size_t)row * HDIM + col] = zv;
          } else {
            int c = col - HDIM;
            float rv = 1.f / (1.f + __expf(-(v + bias1[c])));
            o_a[(size_t)row * HDIM + c] = f2bf(rv * htp[(size_t)row * HDIM + c]);
          }
        } else {
          float hv = tanhf(v + bias0[col]);
          float zv = zout[(size_t)row * HDIM + col];
          float hold = htp[(size_t)row * HDIM + col];
          o_final[(size_t)row * HDIM + col] = (1.f - zv) * hold + zv * hv;
        }
      }
    }
  }
}

extern "C" void kernel_launch(void* const* d_in, const int* in_sizes, int n_in,
                              void* d_out, int out_size, void* d_ws, size_t ws_size,
                              hipStream_t stream) {
  const float* x  = (const float*)d_in[0];
  const float* ht = (const float*)d_in[1];
  const float* Wz = (const float*)d_in[2];
  const float* Uz = (const float*)d_in[3];
  const float* bz = (const float*)d_in[4];
  const float* Wr = (const float*)d_in[5];
  const float* Ur = (const float*)d_in[6];
  const float* br = (const float*)d_in[7];
  const float* Wh = (const float*)d_in[8];
  const float* Uh = (const float*)d_in[9];
  const float* bh = (const float*)d_in[10];
  float* out = (float*)d_out;

  // workspace layout (total 144 MB)
  char* ws = (char*)d_ws;
  u16* xbf   = (u16*)(ws);                            // 8192x2048 bf16 = 32 MB
  u16* htbf  = (u16*)(ws + (((size_t)32) << 20));     // 32 MB
  u16* abf   = (u16*)(ws + (((size_t)64) << 20));     // 32 MB
  u16* bzrt  = (u16*)(ws + (((size_t)96) << 20));     // 4096x4096 bf16 = 32 MB
  u16* whuht = (u16*)(ws + (((size_t)128) << 20));    // 2048x4096 bf16 = 16 MB

  // 1) casts
  cast_bf<<<dim3(2 * 8192 * HDIM / 4 / 256), 256, 0, stream>>>(x, ht, xbf, htbf);

  // 2) weight transposes into B^T layouts
  dim3 tgrid(64, 64);
  transpose_cast<<<tgrid, 256, 0, stream>>>(Wz, bzrt, 4096);
  transpose_cast<<<tgrid, 256, 0, stream>>>(Uz, bzrt + 2048, 4096);
  transpose_cast<<<tgrid, 256, 0, stream>>>(Wr, bzrt + (size_t)2048 * 4096, 4096);
  transpose_cast<<<tgrid, 256, 0, stream>>>(Ur, bzrt + (size_t)2048 * 4096 + 2048, 4096);
  transpose_cast<<<tgrid, 256, 0, stream>>>(Wh, whuht, 4096);
  transpose_cast<<<tgrid, 256, 0, stream>>>(Uh, whuht + 2048, 4096);

  // 3) G1: [x|ht] @ [[Wz,Wr],[Uz,Ur]] (M=8192,N=4096,K=4096) + gate epilogue
  //    z (f32) is written into d_out (scratch until Gh overwrites it).
  gemm2<1><<<dim3(32, 64), 256, 0, stream>>>(xbf, htbf, bzrt, 4096, 4096,
      bz, br, ht, out, abf, nullptr);

  // 4) Gh: [x|a] @ [Wh;Uh] (M=8192,N=2048,K=4096) + final combine
  gemm2<2><<<dim3(16, 64), 256, 0, stream>>>(xbf, abf, whuht, 4096, 4096,
      bh, nullptr, ht, out, nullptr, out);
}

// Round 6
// 878.243 us; speedup vs baseline: 1.0364x; 1.0364x over previous
//
#include <hip/hip_runtime.h>
#include <hip/hip_bf16.h>

typedef unsigned short u16;
typedef __attribute__((ext_vector_type(4))) float f32x4;
typedef __attribute__((ext_vector_type(8))) short bf16x8;
typedef __attribute__((ext_vector_type(4))) unsigned short u16x4;

#define HDIM 2048

__device__ __forceinline__ u16 f2bf(float f) {
  union { float f; unsigned u; } v; v.f = f;
  unsigned r = v.u + 0x7FFFu + ((v.u >> 16) & 1u);
  return (u16)(r >> 16);
}
__device__ __forceinline__ float bf2f(u16 h) {
  union { unsigned u; float f; } v; v.u = ((unsigned)h) << 16;
  return v.f;
}
__device__ __forceinline__ void gload_lds16(const u16* g, void* l) {
  __builtin_amdgcn_global_load_lds(
      (const __attribute__((address_space(1))) unsigned*)g,
      (__attribute__((address_space(3))) unsigned*)l, 16, 0, 0);
}
__device__ __forceinline__ f32x4 mfma16(bf16x8 a, bf16x8 b, f32x4 c) {
  return __builtin_amdgcn_mfma_f32_16x16x32_bf16(a, b, c, 0, 0, 0);
}

// ---- cast two f32 [8192][2048] tensors to bf16 ----
__global__ __launch_bounds__(256) void cast_bf(const float* __restrict__ x,
                                               const float* __restrict__ ht,
                                               u16* __restrict__ xb,
                                               u16* __restrict__ hb) {
  const int N4 = 8192 * HDIM / 4;
  int idx = blockIdx.x * 256 + threadIdx.x;
  const float* s; u16* d; int i;
  if (idx < N4) { s = x; d = xb; i = idx; }
  else          { s = ht; d = hb; i = idx - N4; }
  f32x4 v = *(const f32x4*)(s + (size_t)i * 4);
  u16x4 o;
  o.x = f2bf(v.x); o.y = f2bf(v.y); o.z = f2bf(v.z); o.w = f2bf(v.w);
  *(u16x4*)(d + (size_t)i * 4) = o;
}

// ---- fused transpose+cast of all 6 weights (grid.z selects) ----
__global__ __launch_bounds__(256) void transpose_cast6(
    const float* __restrict__ Wz, const float* __restrict__ Uz,
    const float* __restrict__ Wr, const float* __restrict__ Ur,
    const float* __restrict__ Wh, const float* __restrict__ Uh,
    u16* __restrict__ bzrt, u16* __restrict__ whuht) {
  __shared__ float tile[32][33];
  int z = blockIdx.z;
  const float* src; u16* dst;
  switch (z) {
    case 0: src = Wz; dst = bzrt; break;
    case 1: src = Uz; dst = bzrt + 2048; break;
    case 2: src = Wr; dst = bzrt + (size_t)2048 * 4096; break;
    case 3: src = Ur; dst = bzrt + (size_t)2048 * 4096 + 2048; break;
    case 4: src = Wh; dst = whuht; break;
    default: src = Uh; dst = whuht + 2048; break;
  }
  int tx = threadIdx.x & 31, ty = threadIdx.x >> 5;
  int n0 = blockIdx.x * 32, k0 = blockIdx.y * 32;
#pragma unroll
  for (int i = 0; i < 32; i += 8)
    tile[ty + i][tx] = src[(size_t)(k0 + ty + i) * HDIM + n0 + tx];
  __syncthreads();
#pragma unroll
  for (int i = 0; i < 32; i += 8)
    dst[(size_t)(n0 + ty + i) * 4096 + k0 + tx] = f2bf(tile[tx][ty + i]);
}

// ---- 256x256 8-phase GEMM: C = [A0|A1](bf16,[8192][2048]) x Bt(bf16,[N][4096])^T
// EPI 1: gate epilogue (z -> f32 zout, a = sigmoid(.)*ht -> bf16 o_a).
// EPI 2: final GRU combine (reads zout, writes f32 o_final; aliases zout).
template <int EPI>
__global__ __launch_bounds__(512, 2) void gemm8p(
    const u16* __restrict__ A0g, const u16* __restrict__ A1g,
    const u16* __restrict__ Btg,
    const float* __restrict__ bias0, const float* __restrict__ bias1,
    const float* __restrict__ htp,
    float* zout, u16* __restrict__ o_a, float* o_final)
{
  __shared__ __attribute__((aligned(16))) char lds[131072];
  const int K = 4096, K0 = 2048, NT = 64;
  const int t = threadIdx.x;
  const int lane = t & 63;
  const int w = t >> 6;
  const int wm = w >> 2, wn = w & 3;

  // XCD-aware bijective swizzle (nwg % 8 == 0); chunk walks M (shared B-panel)
  int nwg = gridDim.x;
  int bid = blockIdx.x;
  int swz = (bid & 7) * (nwg >> 3) + (bid >> 3);
  const int m0 = (swz & 31) * 256;
  const int n0 = (swz >> 5) * 256;

  // staging constants: thread T writes 16B at linear slot T*16 of a half-tile;
  // source k-chunk pre-swizzled with the same involution as the read side.
  const int rowT = t >> 2;
  const int srcChunk = (t & 3) ^ ((t >> 3) & 3);
  const int dstOff = t * 16;

  // fragment-read constants: chunk c' = khi ^ ((row>>1)&3)
  const int lrow = lane & 15;
  const int khi_l = lane >> 4;
  const int chunk = khi_l ^ ((lrow >> 1) & 3);
  const int abase = wm * 8192 + lrow * 64 + chunk * 16;
  const int bbase = wn * 4096 + lrow * 64 + chunk * 16;

  f32x4 acc[8][4];
#pragma unroll
  for (int i = 0; i < 8; ++i)
#pragma unroll
    for (int j = 0; j < 4; ++j) acc[i][j] = (f32x4){0.f, 0.f, 0.f, 0.f};

  // sub-buffers per dbuf: 0:A_klo 1:A_khi 2:B_klo 3:B_khi (16KB each)
  auto issueHalf = [&](char* bufbase, int kt, int sub) {
    int kbase = kt * 64 + (sub & 1) * 32 + srcChunk * 8;
    char* dst = bufbase + sub * 16384 + dstOff;
    if (sub < 2) {
      const u16* Ap = A0g; int kk = kbase;
      if (kbase >= K0) { Ap = A1g; kk = kbase - K0; }
      gload_lds16(Ap + (size_t)(m0 + rowT) * K0 + kk, dst);
      gload_lds16(Ap + (size_t)(m0 + 128 + rowT) * K0 + kk, dst + 8192);
    } else {
      gload_lds16(Btg + (size_t)(n0 + rowT) * K + kbase, dst);
      gload_lds16(Btg + (size_t)(n0 + 128 + rowT) * K + kbase, dst + 8192);
    }
  };

  // prologue: stage tile 0 in order A_klo, B_klo, A_khi, B_khi
  issueHalf(lds, 0, 0); issueHalf(lds, 0, 2);
  issueHalf(lds, 0, 1); issueHalf(lds, 0, 3);
  asm volatile("s_waitcnt vmcnt(4)" ::: "memory");   // A_klo,B_klo landed
  __builtin_amdgcn_s_barrier();

  bf16x8 Af[8], B0f[2], B1f[2], B2f[2], B3f[2];
  {
    const char* Bklo = lds + 32768;
    B0f[0] = *(const bf16x8*)(Bklo + bbase);
    B0f[1] = *(const bf16x8*)(Bklo + bbase + 1024);
  }

  for (int kt = 0; kt < NT; ++kt) {
    char* curb = lds + (kt & 1) * 65536;
    char* nxtb = lds + (((kt & 1) ^ 1)) * 65536;
    const char* Aklo = curb;
    const char* Akhi = curb + 16384;
    const char* Bklo = curb + 32768;
    const char* Bkhi = curb + 49152;
    const bool pf = (kt + 1 < NT);

    // ---- P1: MFMA(klo,qn0); read A_klo + B1(klo,qn1); issue A_klo(t+1)
    if (pf) issueHalf(nxtb, kt + 1, 0);
#pragma unroll
    for (int mi = 0; mi < 8; ++mi)
      Af[mi] = *(const bf16x8*)(Aklo + abase + mi * 1024);
    B1f[0] = *(const bf16x8*)(Bklo + bbase + 2048);
    B1f[1] = *(const bf16x8*)(Bklo + bbase + 3072);
    __builtin_amdgcn_s_setprio(1);
#pragma unroll
    for (int mi = 0; mi < 8; ++mi) {
      acc[mi][0] = mfma16(Af[mi], B0f[0], acc[mi][0]);
      acc[mi][1] = mfma16(Af[mi], B0f[1], acc[mi][1]);
    }
    __builtin_amdgcn_s_setprio(0);
    if (pf) { asm volatile("s_waitcnt vmcnt(2)" ::: "memory"); }  // A_khi,B_khi(t) landed
    else    { asm volatile("s_waitcnt vmcnt(0)" ::: "memory"); }
    __builtin_amdgcn_s_barrier();

    // ---- P2: MFMA(klo,qn1); read B2(khi,qn0); issue B_klo(t+1)
    if (pf) issueHalf(nxtb, kt + 1, 2);
    B2f[0] = *(const bf16x8*)(Bkhi + bbase);
    B2f[1] = *(const bf16x8*)(Bkhi + bbase + 1024);
    __builtin_amdgcn_s_setprio(1);
#pragma unroll
    for (int mi = 0; mi < 8; ++mi) {
      acc[mi][2] = mfma16(Af[mi], B1f[0], acc[mi][2]);
      acc[mi][3] = mfma16(Af[mi], B1f[1], acc[mi][3]);
    }
    __builtin_amdgcn_s_setprio(0);
    __builtin_amdgcn_s_barrier();

    // ---- P3: MFMA(khi,qn0); read A_khi + B3(khi,qn1); issue A_khi(t+1)
    if (pf) issueHalf(nxtb, kt + 1, 1);
#pragma unroll
    for (int mi = 0; mi < 8; ++mi)
      Af[mi] = *(const bf16x8*)(Akhi + abase + mi * 1024);
    B3f[0] = *(const bf16x8*)(Bkhi + bbase + 2048);
    B3f[1] = *(const bf16x8*)(Bkhi + bbase + 3072);
    __builtin_amdgcn_s_setprio(1);
#pragma unroll
    for (int mi = 0; mi < 8; ++mi) {
      acc[mi][0] = mfma16(Af[mi], B2f[0], acc[mi][0]);
      acc[mi][1] = mfma16(Af[mi], B2f[1], acc[mi][1]);
    }
    __builtin_amdgcn_s_setprio(0);
    asm volatile("s_waitcnt vmcnt(2)" ::: "memory");  // A_klo,B_klo(t+1) landed
    __builtin_amdgcn_s_barrier();

    // ---- P4: MFMA(khi,qn1); read B0(klo,qn0,t+1); issue B_khi(t+1)
    if (pf) issueHalf(nxtb, kt + 1, 3);
    if (pf) {
      const char* BkloN = nxtb + 32768;
      B0f[0] = *(const bf16x8*)(BkloN + bbase);
      B0f[1] = *(const bf16x8*)(BkloN + bbase + 1024);
    }
    __builtin_amdgcn_s_setprio(1);
#pragma unroll
    for (int mi = 0; mi < 8; ++mi) {
      acc[mi][2] = mfma16(Af[mi], B3f[0], acc[mi][2]);
      acc[mi][3] = mfma16(Af[mi], B3f[1], acc[mi][3]);
    }
    __builtin_amdgcn_s_setprio(0);
    __builtin_amdgcn_s_barrier();
  }

  // epilogue: C/D layout col = lane&15, row = (lane>>4)*4 + reg  [m89/m91]
  const int rbase = (lane >> 4) * 4;
  const int cbase = lane & 15;
#pragma unroll
  for (int mi = 0; mi < 8; ++mi) {
#pragma unroll
    for (int ni = 0; ni < 4; ++ni) {
#pragma unroll
      for (int j = 0; j < 4; ++j) {
        int row = m0 + wm * 128 + mi * 16 + rbase + j;
        int col = n0 + wn * 64 + ni * 16 + cbase;
        float v = acc[mi][ni][j];
        if constexpr (EPI == 1) {
          if (col < HDIM) {
            float zv = 1.f / (1.f + __expf(-(v + bias0[col])));
            zout[(size_t)row * HDIM + col] = zv;
          } else {
            int c = col - HDIM;
            float rv = 1.f / (1.f + __expf(-(v + bias1[c])));
            o_a[(size_t)row * HDIM + c] = f2bf(rv * htp[(size_t)row * HDIM + c]);
          }
        } else {
          float hv = tanhf(v + bias0[col]);
          float zv = zout[(size_t)row * HDIM + col];
          float hold = htp[(size_t)row * HDIM + col];
          o_final[(size_t)row * HDIM + col] = (1.f - zv) * hold + zv * hv;
        }
      }
    }
  }
}

extern "C" void kernel_launch(void* const* d_in, const int* in_sizes, int n_in,
                              void* d_out, int out_size, void* d_ws, size_t ws_size,
                              hipStream_t stream) {
  const float* x  = (const float*)d_in[0];
  const float* ht = (const float*)d_in[1];
  const float* Wz = (const float*)d_in[2];
  const float* Uz = (const float*)d_in[3];
  const float* bz = (const float*)d_in[4];
  const float* Wr = (const float*)d_in[5];
  const float* Ur = (const float*)d_in[6];
  const float* br = (const float*)d_in[7];
  const float* Wh = (const float*)d_in[8];
  const float* Uh = (const float*)d_in[9];
  const float* bh = (const float*)d_in[10];
  float* out = (float*)d_out;

  // workspace layout (total 144 MB)
  char* ws = (char*)d_ws;
  u16* xbf   = (u16*)(ws);                            // 8192x2048 bf16 = 32 MB
  u16* htbf  = (u16*)(ws + (((size_t)32) << 20));     // 32 MB
  u16* abf   = (u16*)(ws + (((size_t)64) << 20));     // 32 MB
  u16* bzrt  = (u16*)(ws + (((size_t)96) << 20));     // 4096x4096 bf16 = 32 MB
  u16* whuht = (u16*)(ws + (((size_t)128) << 20));    // 2048x4096 bf16 = 16 MB

  // 1) casts
  cast_bf<<<dim3(2 * 8192 * HDIM / 4 / 256), 256, 0, stream>>>(x, ht, xbf, htbf);

  // 2) all 6 weight transposes in one launch
  transpose_cast6<<<dim3(64, 64, 6), 256, 0, stream>>>(Wz, Uz, Wr, Ur, Wh, Uh,
                                                       bzrt, whuht);

  // 3) G1: [x|ht] @ [[Wz,Wr],[Uz,Ur]] (M=8192,N=4096,K=4096) + gate epilogue
  //    z (f32) goes into d_out (scratch until Gh overwrites it).
  gemm8p<1><<<dim3(512), 512, 0, stream>>>(xbf, htbf, bzrt,
      bz, br, ht, out, abf, nullptr);

  // 4) Gh: [x|a] @ [Wh;Uh] (M=8192,N=2048,K=4096) + final combine
  gemm8p<2><<<dim3(256), 512, 0, stream>>>(xbf, abf, whuht,
      bh, nullptr, ht, out, nullptr, out);
}

// Round 7
// 756.121 us; speedup vs baseline: 1.2038x; 1.1615x over previous
//
#include <hip/hip_runtime.h>
#include <hip/hip_bf16.h>

typedef unsigned short u16;
typedef __attribute__((ext_vector_type(4))) float f32x4;
typedef __attribute__((ext_vector_type(8))) short bf16x8;
typedef __attribute__((ext_vector_type(4))) unsigned short u16x4;

#define HDIM 2048

__device__ __forceinline__ u16 f2bf(float f) {
  union { float f; unsigned u; } v; v.f = f;
  unsigned r = v.u + 0x7FFFu + ((v.u >> 16) & 1u);
  return (u16)(r >> 16);
}
__device__ __forceinline__ float bf2f(u16 h) {
  union { unsigned u; float f; } v; v.u = ((unsigned)h) << 16;
  return v.f;
}
__device__ __forceinline__ void gload_lds16(const u16* g, void* l) {
  __builtin_amdgcn_global_load_lds(
      (const __attribute__((address_space(1))) unsigned*)g,
      (__attribute__((address_space(3))) unsigned*)l, 16, 0, 0);
}
__device__ __forceinline__ f32x4 mfma16(bf16x8 a, bf16x8 b, f32x4 c) {
  return __builtin_amdgcn_mfma_f32_16x16x32_bf16(a, b, c, 0, 0, 0);
}

// ---- cast two f32 [8192][2048] tensors to bf16 ----
__global__ __launch_bounds__(256) void cast_bf(const float* __restrict__ x,
                                               const float* __restrict__ ht,
                                               u16* __restrict__ xb,
                                               u16* __restrict__ hb) {
  const int N4 = 8192 * HDIM / 4;
  int idx = blockIdx.x * 256 + threadIdx.x;
  const float* s; u16* d; int i;
  if (idx < N4) { s = x; d = xb; i = idx; }
  else          { s = ht; d = hb; i = idx - N4; }
  f32x4 v = *(const f32x4*)(s + (size_t)i * 4);
  u16x4 o;
  o.x = f2bf(v.x); o.y = f2bf(v.y); o.z = f2bf(v.z); o.w = f2bf(v.w);
  *(u16x4*)(d + (size_t)i * 4) = o;
}

// ---- fused transpose+cast of all 6 weights (grid.z selects) ----
__global__ __launch_bounds__(256) void transpose_cast6(
    const float* __restrict__ Wz, const float* __restrict__ Uz,
    const float* __restrict__ Wr, const float* __restrict__ Ur,
    const float* __restrict__ Wh, const float* __restrict__ Uh,
    u16* __restrict__ bzrt, u16* __restrict__ whuht) {
  __shared__ float tile[32][33];
  int z = blockIdx.z;
  const float* src; u16* dst;
  switch (z) {
    case 0: src = Wz; dst = bzrt; break;
    case 1: src = Uz; dst = bzrt + 2048; break;
    case 2: src = Wr; dst = bzrt + (size_t)2048 * 4096; break;
    case 3: src = Ur; dst = bzrt + (size_t)2048 * 4096 + 2048; break;
    case 4: src = Wh; dst = whuht; break;
    default: src = Uh; dst = whuht + 2048; break;
  }
  int tx = threadIdx.x & 31, ty = threadIdx.x >> 5;
  int n0 = blockIdx.x * 32, k0 = blockIdx.y * 32;
#pragma unroll
  for (int i = 0; i < 32; i += 8)
    tile[ty + i][tx] = src[(size_t)(k0 + ty + i) * HDIM + n0 + tx];
  __syncthreads();
#pragma unroll
  for (int i = 0; i < 32; i += 8)
    dst[(size_t)(n0 + ty + i) * 4096 + k0 + tx] = f2bf(tile[tx][ty + i]);
}

// ---- 256x256 8-phase GEMM: C = [A0|A1](bf16,[8192][2048]) x Bt(bf16,[N][4096])^T
// Phase shape per m201 template: {ds_read own frags; issue 1 half-tile;
//  s_barrier; lgkmcnt(0)+sched_barrier(0); setprio1; 16 MFMA; setprio0;
//  [vmcnt(4) at P2/P4]; s_barrier}.  NTN_LOG2: log2 of N-tiles (16 or 8).
template <int EPI, int NTN_LOG2>
__global__ __launch_bounds__(512, 2) void gemm8p(
    const u16* __restrict__ A0g, const u16* __restrict__ A1g,
    const u16* __restrict__ Btg,
    const float* __restrict__ bias0, const float* __restrict__ bias1,
    const float* __restrict__ htp,
    float* zout, u16* __restrict__ o_a, float* o_final)
{
  __shared__ __attribute__((aligned(16))) char lds[131072];
  const int K = 4096, K0 = 2048, NT = 64;
  const int t = threadIdx.x;
  const int lane = t & 63;
  const int w = t >> 6;
  const int wm = w >> 2, wn = w & 3;

  // XCD L2-locality mapping: each XCD owns a 4-M-tile band; within an XCD the
  // 32 concurrent blocks form a 4M x 8N patch (A K-slices + B K-slices L2-fit).
  int bid = blockIdx.x;
  int r = bid >> 3;
  int g = r >> 5, inner = r & 31;
  const int m0 = ((bid & 7) * 4 + (inner & 3)) * 256;
  const int n0 = ((g << 3) + (inner >> 2)) * 256;

  // staging: thread T writes 16B at linear slot T*16 of a half-tile; source
  // k-chunk pre-swizzled with the same involution used on the read side.
  const int rowT = t >> 2;
  const int srcChunk = (t & 3) ^ ((t >> 3) & 3);
  const int dstOff = t * 16;

  // fragment-read: chunk = khi ^ ((lrow>>1)&3)  (2-way bank alias only = free)
  const int lrow = lane & 15;
  const int khi_l = lane >> 4;
  const int chunk = khi_l ^ ((lrow >> 1) & 3);
  const int abase = wm * 8192 + lrow * 64 + chunk * 16;
  const int bbase = wn * 4096 + lrow * 64 + chunk * 16;

  f32x4 acc[8][4];
#pragma unroll
  for (int i = 0; i < 8; ++i)
#pragma unroll
    for (int j = 0; j < 4; ++j) acc[i][j] = (f32x4){0.f, 0.f, 0.f, 0.f};

  // sub-buffers per dbuf: 0:A_klo(+0) 1:A_khi(+16384) 2:B_klo(+32768) 3:B_khi(+49152)
  auto issueHalf = [&](char* bufbase, int kt, int sub) {
    int kbase = kt * 64 + (sub & 1) * 32 + srcChunk * 8;
    char* dst = bufbase + sub * 16384 + dstOff;
    if (sub < 2) {
      const u16* Ap = A0g; int kk = kbase;
      if (kbase >= K0) { Ap = A1g; kk = kbase - K0; }
      gload_lds16(Ap + (size_t)(m0 + rowT) * K0 + kk, dst);
      gload_lds16(Ap + (size_t)(m0 + 128 + rowT) * K0 + kk, dst + 8192);
    } else {
      gload_lds16(Btg + (size_t)(n0 + rowT) * K + kbase, dst);
      gload_lds16(Btg + (size_t)(n0 + 128 + rowT) * K + kbase, dst + 8192);
    }
  };

  // prologue: issue tile-0 halves in order A_klo, B_klo, A_khi, B_khi;
  // retire klo pair -> enter loop exactly in the steady-state invariant
  // (in-flight = khi(0) = 4 loads/thread).
  issueHalf(lds, 0, 0); issueHalf(lds, 0, 2);
  issueHalf(lds, 0, 1); issueHalf(lds, 0, 3);
  asm volatile("s_waitcnt vmcnt(4)" ::: "memory");
  __builtin_amdgcn_s_barrier();

  bf16x8 Af[8], Bf[2];

  for (int kt = 0; kt < NT; ++kt) {
    char* curb = lds + (kt & 1) * 65536;
    char* nxtb = lds + ((kt & 1) ^ 1) * 65536;
    const char* Aklo = curb;
    const char* Akhi = curb + 16384;
    const char* Bklo = curb + 32768;
    const char* Bkhi = curb + 49152;
    const bool pf = (kt + 1 < NT);

    // ---- P1: frags Aklo + B(klo,ni0:1); issue A_klo(t+1); MFMA acc[][0:1]
#pragma unroll
    for (int mi = 0; mi < 8; ++mi)
      Af[mi] = *(const bf16x8*)(Aklo + abase + mi * 1024);
    Bf[0] = *(const bf16x8*)(Bklo + bbase);
    Bf[1] = *(const bf16x8*)(Bklo + bbase + 1024);
    if (pf) issueHalf(nxtb, kt + 1, 0);
    __builtin_amdgcn_s_barrier();
    asm volatile("s_waitcnt lgkmcnt(0)" ::: "memory");
    __builtin_amdgcn_sched_barrier(0);
    __builtin_amdgcn_s_setprio(1);
#pragma unroll
    for (int mi = 0; mi < 8; ++mi) {
      acc[mi][0] = mfma16(Af[mi], Bf[0], acc[mi][0]);
      acc[mi][1] = mfma16(Af[mi], Bf[1], acc[mi][1]);
    }
    __builtin_amdgcn_s_setprio(0);
    __builtin_amdgcn_s_barrier();

    // ---- P2: frags B(klo,ni2:3); issue B_klo(t+1); MFMA acc[][2:3]; vmcnt
    Bf[0] = *(const bf16x8*)(Bklo + bbase + 2048);
    Bf[1] = *(const bf16x8*)(Bklo + bbase + 3072);
    if (pf) issueHalf(nxtb, kt + 1, 2);
    __builtin_amdgcn_s_barrier();
    asm volatile("s_waitcnt lgkmcnt(0)" ::: "memory");
    __builtin_amdgcn_sched_barrier(0);
    __builtin_amdgcn_s_setprio(1);
#pragma unroll
    for (int mi = 0; mi < 8; ++mi) {
      acc[mi][2] = mfma16(Af[mi], Bf[0], acc[mi][2]);
      acc[mi][3] = mfma16(Af[mi], Bf[1], acc[mi][3]);
    }
    __builtin_amdgcn_s_setprio(0);
    if (pf) { asm volatile("s_waitcnt vmcnt(4)" ::: "memory"); }  // khi(t) landed
    else    { asm volatile("s_waitcnt vmcnt(0)" ::: "memory"); }
    __builtin_amdgcn_s_barrier();

    // ---- P3: frags Akhi + B(khi,ni0:1); issue A_khi(t+1); MFMA acc[][0:1]
#pragma unroll
    for (int mi = 0; mi < 8; ++mi)
      Af[mi] = *(const bf16x8*)(Akhi + abase + mi * 1024);
    Bf[0] = *(const bf16x8*)(Bkhi + bbase);
    Bf[1] = *(const bf16x8*)(Bkhi + bbase + 1024);
    if (pf) issueHalf(nxtb, kt + 1, 1);
    __builtin_amdgcn_s_barrier();
    asm volatile("s_waitcnt lgkmcnt(0)" ::: "memory");
    __builtin_amdgcn_sched_barrier(0);
    __builtin_amdgcn_s_setprio(1);
#pragma unroll
    for (int mi = 0; mi < 8; ++mi) {
      acc[mi][0] = mfma16(Af[mi], Bf[0], acc[mi][0]);
      acc[mi][1] = mfma16(Af[mi], Bf[1], acc[mi][1]);
    }
    __builtin_amdgcn_s_setprio(0);
    __builtin_amdgcn_s_barrier();

    // ---- P4: frags B(khi,ni2:3); issue B_khi(t+1); MFMA acc[][2:3]; vmcnt
    Bf[0] = *(const bf16x8*)(Bkhi + bbase + 2048);
    Bf[1] = *(const bf16x8*)(Bkhi + bbase + 3072);
    if (pf) issueHalf(nxtb, kt + 1, 3);
    __builtin_amdgcn_s_barrier();
    asm volatile("s_waitcnt lgkmcnt(0)" ::: "memory");
    __builtin_amdgcn_sched_barrier(0);
    __builtin_amdgcn_s_setprio(1);
#pragma unroll
    for (int mi = 0; mi < 8; ++mi) {
      acc[mi][2] = mfma16(Af[mi], Bf[0], acc[mi][2]);
      acc[mi][3] = mfma16(Af[mi], Bf[1], acc[mi][3]);
    }
    __builtin_amdgcn_s_setprio(0);
    if (pf) { asm volatile("s_waitcnt vmcnt(4)" ::: "memory"); }  // klo(t+1) landed
    __builtin_amdgcn_s_barrier();
  }

  // epilogue: C/D layout col = lane&15, row = (lane>>4)*4 + reg  [m89/m91]
  const int rbase = (lane >> 4) * 4;
  const int cbase = lane & 15;
#pragma unroll
  for (int mi = 0; mi < 8; ++mi) {
#pragma unroll
    for (int ni = 0; ni < 4; ++ni) {
#pragma unroll
      for (int j = 0; j < 4; ++j) {
        int row = m0 + wm * 128 + mi * 16 + rbase + j;
        int col = n0 + wn * 64 + ni * 16 + cbase;
        float v = acc[mi][ni][j];
        if constexpr (EPI == 1) {
          if (col < HDIM) {
            float zv = 1.f / (1.f + __expf(-(v + bias0[col])));
            zout[(size_t)row * HDIM + col] = zv;
          } else {
            int c = col - HDIM;
            float rv = 1.f / (1.f + __expf(-(v + bias1[c])));
            o_a[(size_t)row * HDIM + c] = f2bf(rv * htp[(size_t)row * HDIM + c]);
          }
        } else {
          float hv = tanhf(v + bias0[col]);
          float zv = zout[(size_t)row * HDIM + col];
          float hold = htp[(size_t)row * HDIM + col];
          o_final[(size_t)row * HDIM + col] = (1.f - zv) * hold + zv * hv;
        }
      }
    }
  }
}

extern "C" void kernel_launch(void* const* d_in, const int* in_sizes, int n_in,
                              void* d_out, int out_size, void* d_ws, size_t ws_size,
                              hipStream_t stream) {
  const float* x  = (const float*)d_in[0];
  const float* ht = (const float*)d_in[1];
  const float* Wz = (const float*)d_in[2];
  const float* Uz = (const float*)d_in[3];
  const float* bz = (const float*)d_in[4];
  const float* Wr = (const float*)d_in[5];
  const float* Ur = (const float*)d_in[6];
  const float* br = (const float*)d_in[7];
  const float* Wh = (const float*)d_in[8];
  const float* Uh = (const float*)d_in[9];
  const float* bh = (const float*)d_in[10];
  float* out = (float*)d_out;

  // workspace layout (total 144 MB)
  char* ws = (char*)d_ws;
  u16* xbf   = (u16*)(ws);                            // 8192x2048 bf16 = 32 MB
  u16* htbf  = (u16*)(ws + (((size_t)32) << 20));     // 32 MB
  u16* abf   = (u16*)(ws + (((size_t)64) << 20));     // 32 MB
  u16* bzrt  = (u16*)(ws + (((size_t)96) << 20));     // 4096x4096 bf16 = 32 MB
  u16* whuht = (u16*)(ws + (((size_t)128) << 20));    // 2048x4096 bf16 = 16 MB

  // 1) casts
  cast_bf<<<dim3(2 * 8192 * HDIM / 4 / 256), 256, 0, stream>>>(x, ht, xbf, htbf);

  // 2) all 6 weight transposes in one launch
  transpose_cast6<<<dim3(64, 64, 6), 256, 0, stream>>>(Wz, Uz, Wr, Ur, Wh, Uh,
                                                       bzrt, whuht);

  // 3) G1: [x|ht] @ [[Wz,Wr],[Uz,Ur]] (M=8192,N=4096,K=4096) + gate epilogue
  //    z (f32) goes into d_out (scratch until Gh overwrites it).
  gemm8p<1, 4><<<dim3(512), 512, 0, stream>>>(xbf, htbf, bzrt,
      bz, br, ht, out, abf, nullptr);

  // 4) Gh: [x|a] @ [Wh;Uh] (M=8192,N=2048,K=4096) + final combine
  gemm8p<2, 3><<<dim3(256), 512, 0, stream>>>(xbf, abf, whuht,
      bh, nullptr, ht, out, nullptr, out);
}